// Round 1
// baseline (37.279 us; speedup 1.0000x reference)
//
#include <hip/hip_runtime.h>
#include <math.h>

#define NJ 24
#define NV 6890
#define NB 128

__constant__ int d_parents[NJ] = {-1,0,0,0,1,2,3,4,5,6,7,8,9,9,9,12,13,14,16,17,18,19,20,21};

// Kernel 1: per-batch Rodrigues + kinematic chain + J-correction.
// Writes Gc[b][m][12] (3x4 row-major, col 3 = corrected translation) to ws.
__global__ __launch_bounds__(64) void chain_kernel(const float* __restrict__ J,
                                                   const float* __restrict__ pose,
                                                   float* __restrict__ Gc) {
    int b = blockIdx.x;
    int tid = threadIdx.x;
    __shared__ float Ar[NJ][9];
    __shared__ float At[NJ][3];
    __shared__ float G[NJ][12];

    if (tid < NJ) {
        int i = tid;
        const float* p = pose + ((size_t)b * NJ + i) * 3;
        float rx = p[0], ry = p[1], rz = p[2];
        // theta = norm(r + 1e-8) elementwise-eps, faithful to reference
        float ex = rx + 1e-8f, ey = ry + 1e-8f, ez = rz + 1e-8f;
        float theta = sqrtf(ex * ex + ey * ey + ez * ez);
        float inv = 1.0f / theta;
        float hx = rx * inv, hy = ry * inv, hz = rz * inv;
        // faithful to reference: cos(theta*pi), sin(theta)
        float c = cosf(theta * (float)M_PI);
        float s = sinf(theta);
        float oc = 1.0f - c;
        Ar[i][0] = c + oc * hx * hx;
        Ar[i][1] = oc * hx * hy - s * hz;
        Ar[i][2] = oc * hx * hz + s * hy;
        Ar[i][3] = oc * hy * hx + s * hz;
        Ar[i][4] = c + oc * hy * hy;
        Ar[i][5] = oc * hy * hz - s * hx;
        Ar[i][6] = oc * hz * hx - s * hy;
        Ar[i][7] = oc * hz * hy + s * hx;
        Ar[i][8] = c + oc * hz * hz;
        const float* jp = J + ((size_t)b * NJ + i) * 3;
        int par = d_parents[i];
        if (par < 0) {
            At[i][0] = jp[0]; At[i][1] = jp[1]; At[i][2] = jp[2];
        } else {
            const float* jq = J + ((size_t)b * NJ + par) * 3;
            At[i][0] = jp[0] - jq[0];
            At[i][1] = jp[1] - jq[1];
            At[i][2] = jp[2] - jq[2];
        }
    }
    __syncthreads();

    if (tid == 0) {
        // G[0] = A[0]
        #pragma unroll
        for (int r = 0; r < 3; r++) {
            G[0][r * 4 + 0] = Ar[0][r * 3 + 0];
            G[0][r * 4 + 1] = Ar[0][r * 3 + 1];
            G[0][r * 4 + 2] = Ar[0][r * 3 + 2];
            G[0][r * 4 + 3] = At[0][r];
        }
        for (int i = 1; i < NJ; i++) {
            int p = d_parents[i];
            #pragma unroll
            for (int r = 0; r < 3; r++) {
                float g0 = G[p][r * 4 + 0], g1 = G[p][r * 4 + 1];
                float g2 = G[p][r * 4 + 2], g3 = G[p][r * 4 + 3];
                G[i][r * 4 + 0] = g0 * Ar[i][0] + g1 * Ar[i][3] + g2 * Ar[i][6];
                G[i][r * 4 + 1] = g0 * Ar[i][1] + g1 * Ar[i][4] + g2 * Ar[i][7];
                G[i][r * 4 + 2] = g0 * Ar[i][2] + g1 * Ar[i][5] + g2 * Ar[i][8];
                G[i][r * 4 + 3] = g0 * At[i][0] + g1 * At[i][1] + g2 * At[i][2] + g3;
            }
        }
    }
    __syncthreads();

    if (tid < NJ) {
        int i = tid;
        const float* jp = J + ((size_t)b * NJ + i) * 3;
        float jx = jp[0], jy = jp[1], jz = jp[2];
        float* o = Gc + ((size_t)b * NJ + i) * 12;
        #pragma unroll
        for (int r = 0; r < 3; r++) {
            float g0 = G[i][r * 4 + 0], g1 = G[i][r * 4 + 1];
            float g2 = G[i][r * 4 + 2], g3 = G[i][r * 4 + 3];
            float corr = g0 * jx + g1 * jy + g2 * jz;
            o[r * 4 + 0] = g0;
            o[r * 4 + 1] = g1;
            o[r * 4 + 2] = g2;
            o[r * 4 + 3] = g3 - corr;
        }
    }
}

// Kernel 2: per-vertex skinning. out[b,n] = (sum_m W[b,n,m] * Gc[b,m]) @ [V,1]
__global__ __launch_bounds__(256) void lbs_kernel(const float* __restrict__ V,
                                                  const float* __restrict__ W,
                                                  const float* __restrict__ Gc,
                                                  float* __restrict__ out) {
    int b = blockIdx.y;
    int n = blockIdx.x * 256 + threadIdx.x;
    __shared__ float g[NJ * 12];
    for (int k = threadIdx.x; k < NJ * 12; k += 256)
        g[k] = Gc[(size_t)b * NJ * 12 + k];
    __syncthreads();
    if (n >= NV) return;

    const float4* wp = (const float4*)(W + ((size_t)b * NV + n) * 24);
    float4 w0 = wp[0], w1 = wp[1], w2 = wp[2], w3 = wp[3], w4 = wp[4], w5 = wp[5];
    float w[24] = {w0.x, w0.y, w0.z, w0.w, w1.x, w1.y, w1.z, w1.w,
                   w2.x, w2.y, w2.z, w2.w, w3.x, w3.y, w3.z, w3.w,
                   w4.x, w4.y, w4.z, w4.w, w5.x, w5.y, w5.z, w5.w};

    float T[12];
    #pragma unroll
    for (int j = 0; j < 12; j++) T[j] = 0.0f;
    #pragma unroll
    for (int m = 0; m < NJ; m++) {
        float wm = w[m];
        #pragma unroll
        for (int j = 0; j < 12; j++) T[j] += wm * g[m * 12 + j];
    }

    const float* vp = V + ((size_t)b * NV + n) * 3;
    float vx = vp[0], vy = vp[1], vz = vp[2];
    float ox = T[0] * vx + T[1] * vy + T[2]  * vz + T[3];
    float oy = T[4] * vx + T[5] * vy + T[6]  * vz + T[7];
    float oz = T[8] * vx + T[9] * vy + T[10] * vz + T[11];

    float* op = out + ((size_t)b * NV + n) * 3;
    op[0] = ox;
    op[1] = oy;
    op[2] = oz;
}

extern "C" void kernel_launch(void* const* d_in, const int* in_sizes, int n_in,
                              void* d_out, int out_size, void* d_ws, size_t ws_size,
                              hipStream_t stream) {
    const float* V    = (const float*)d_in[0];
    const float* J    = (const float*)d_in[1];
    const float* pose = (const float*)d_in[2];
    const float* W    = (const float*)d_in[3];
    float* out = (float*)d_out;
    float* Gc  = (float*)d_ws;  // NB*NJ*12 floats = 147456 B

    chain_kernel<<<NB, 64, 0, stream>>>(J, pose, Gc);
    dim3 grid((NV + 255) / 256, NB);
    lbs_kernel<<<grid, 256, 0, stream>>>(V, W, Gc, out);
}